// Round 5
// baseline (1575.491 us; speedup 1.0000x reference)
//
#include <hip/hip_runtime.h>
#include <math.h>

#define NN 50000
#define NE 400000
#define NEP 40000
#define FD 64
#define EDD 32
#define HD 128
#define NL 2
#define HCAP 210000   // per-chunk h-row capacity (chunk mean 200k, sigma ~316)

typedef unsigned short u16;
typedef __attribute__((ext_vector_type(8))) short bf8;   // 8 x bf16 = 16B
typedef __attribute__((ext_vector_type(4))) float f4;    // MFMA accumulator

__device__ __forceinline__ float bf2f(u16 u){ return __uint_as_float(((unsigned)u)<<16); }
__device__ __forceinline__ u16 f2bf(float f){
  unsigned u = __float_as_uint(f);
  u += 0x7FFFu + ((u>>16)&1u);           // RNE
  return (u16)(u>>16);
}
// squash NaN/Inf to 0 (bit-level: robust under any fp flags)
__device__ __forceinline__ float fin(float f){
  unsigned u = __float_as_uint(f);
  return ((u & 0x7F800000u) == 0x7F800000u) ? 0.f : f;
}
// load 8 f32, convert to 8 bf16
__device__ __forceinline__ bf8 ld8f(const float* __restrict__ p){
  float4 a = *(const float4*)p;
  float4 b = *(const float4*)(p+4);
  bf8 o;
  o[0]=(short)f2bf(a.x); o[1]=(short)f2bf(a.y); o[2]=(short)f2bf(a.z); o[3]=(short)f2bf(a.w);
  o[4]=(short)f2bf(b.x); o[5]=(short)f2bf(b.y); o[6]=(short)f2bf(b.z); o[7]=(short)f2bf(b.w);
  return o;
}

// ---------------- setup kernels ----------------
__global__ __launch_bounds__(256) void k_zero(int* __restrict__ p, int n){
  int i = blockIdx.x*256 + threadIdx.x;
  if(i < n) p[i] = 0;
}

__global__ __launch_bounds__(256) void k_deg(const int* __restrict__ ei, int* __restrict__ deg){
  int e = blockIdx.x*256 + threadIdx.x;
  if(e < NE){
    unsigned d = (unsigned)ei[NE+e]; if(d >= NN) d = 0;
    atomicAdd(&deg[d], 1);
  }
}

// avg_deg_log = mean over nodes of log(deg+1)  (recomputed on-device; ignores input scalar)
__global__ __launch_bounds__(1024) void k_adl(const int* __restrict__ deg, float* __restrict__ adlbuf){
  __shared__ float sums[1024];
  int t = threadIdx.x;
  float s = 0.f;
  for(int n = t; n < NN; n += 1024) s += logf((float)deg[n] + 1.0f);
  sums[t] = s;
  __syncthreads();
  for(int off = 512; off > 0; off >>= 1){
    if(t < off) sums[t] += sums[t+off];
    __syncthreads();
  }
  if(t == 0){
    float adl = sums[0] / (float)NN;
    if(!(adl > 1e-6f)) adl = 1.0f;
    adlbuf[0] = adl;
  }
}

__global__ __launch_bounds__(1024) void k_scan(const int* __restrict__ deg, int* __restrict__ rowptr){
  __shared__ int sums[1024];
  int t = threadIdx.x;
  const int CH = (NN + 1023)/1024;   // 49
  int st = t*CH;
  int local = 0;
  for(int i=0;i<CH;i++){ int n = st+i; if(n<NN) local += deg[n]; }
  sums[t] = local;
  __syncthreads();
  for(int off=1; off<1024; off<<=1){
    int v = sums[t];
    int add = (t>=off) ? sums[t-off] : 0;
    __syncthreads();
    sums[t] = v + add;
    __syncthreads();
  }
  int run = sums[t] - local;          // exclusive prefix
  for(int i=0;i<CH;i++){ int n = st+i; if(n<NN){ rowptr[n] = run; run += deg[n]; } }
  if(t==0) rowptr[NN] = NE;
}

__global__ __launch_bounds__(256) void k_nodeprep(const int* __restrict__ deg, const float* __restrict__ adlbuf,
                                                  float* __restrict__ amp, float* __restrict__ att){
  int n = blockIdx.x*256 + threadIdx.x;
  if(n >= NN) return;
  float adl = adlbuf[0];
  int d = deg[n]; if(d < 1) d = 1;
  float lg = logf((float)d + 1.0f);
  float a1 = lg/adl, a2 = adl/lg;
  a1 = fminf(fmaxf(a1, 1e-6f), 1e4f);
  a2 = fminf(fmaxf(a2, 1e-6f), 1e4f);
  amp[n] = a1;
  att[n] = a2;
}

__global__ __launch_bounds__(256) void k_fill(const int* __restrict__ ei, const int* __restrict__ rowptr,
                                              int* __restrict__ cursor, int* __restrict__ eids){
  int e = blockIdx.x*256 + threadIdx.x;
  if(e >= NE) return;
  unsigned d = (unsigned)ei[NE+e]; if(d >= NN) d = 0;
  int c = atomicAdd(&cursor[d], 1);
  eids[rowptr[d] + c] = e;
}

// fold eenc into pre:  Bp = [pre_w[0:256] ; eenc_w @ pre_w[256:384]] (bf16),
// biasH = eenc_b@pre_w[256:] + pre_b (f32).  All weight inputs f32.
__global__ __launch_bounds__(256) void k_fold_pre(const float* __restrict__ eenc_w, const float* __restrict__ eenc_b,
                   const float* __restrict__ pre_w, const float* __restrict__ pre_b,
                   u16* __restrict__ Bp, float* __restrict__ biasH){
  int l = blockIdx.x, t = threadIdx.x;
  const float* EW = eenc_w + l*HD*HD;
  const float* PW = pre_w  + l*384*HD;
  u16* out = Bp + l*384*HD;
  for(int i=t; i<256*HD; i+=256) out[i] = f2bf(PW[i]);
  for(int i=t; i<HD*HD; i+=256){
    int k = i>>7, c = i&127;
    float s = 0.f;
    for(int j=0;j<HD;j++) s += EW[k*HD+j] * PW[(256+j)*HD + c];
    out[(256+k)*HD + c] = f2bf(s);
  }
  if(t < HD){
    float s = pre_b[l*HD + t];
    for(int j=0;j<HD;j++) s += eenc_b[l*HD+j] * PW[(256+j)*HD + t];
    biasH[l*HD + t] = s;
  }
}

// repack weight matrices [K][128] into per-(kstep,colfrag,lane) contiguous MFMA B-fragments.
// per-job flag: src is f32 (1) or bf16 (0)
#define NJOBS 12
struct FragJobs {
  const void* src[NJOBS];
  u16* dst[NJOBS];
  int end[NJOBS];   // cumulative unit counts; units per job = K*16
  int isf32[NJOBS];
};
__global__ __launch_bounds__(256) void k_fragB(FragJobs J){
  int u = blockIdx.x*256 + threadIdx.x;
  int j = 0, start = 0;
  while(j < NJOBS && u >= J.end[j]){ start = J.end[j]; j++; }
  if(j >= NJOBS) return;
  int lu = u - start;
  int lane = lu & 63, cf = (lu>>6)&7, ks = lu>>9;
  u16* d = J.dst[j];
  #pragma unroll
  for(int i=0;i<8;i++){
    size_t si = (size_t)(ks*32 + (lane>>4)*8 + i)*HD + cf*16 + (lane&15);
    u16 v = J.isf32[j] ? f2bf(((const float*)J.src[j])[si]) : ((const u16*)J.src[j])[si];
    d[((size_t)((ks*8+cf)*64 + lane))*8 + i] = v;
  }
}

// ---------------- GEMM kernels ----------------
// A [M,K] f32 row-major @ Wfrag -> C [M,128]; obf=1: bf16 out, obf=0: f32 out
__global__ __launch_bounds__(256) void k_gemm_rm(const float* __restrict__ A, const u16* __restrict__ Wf,
      const float* __restrict__ bias, void* __restrict__ C, int M, int K, int obf)
{
  __shared__ __align__(16) u16 At[128*40];
  __shared__ __align__(16) u16 Ot[128*136];
  int tid = threadIdx.x, lane = tid&63, wv = tid>>6;
  int quad = lane>>4, l16 = lane&15;
  int rbase = blockIdx.x*128;
  f4 zero4 = {0.f,0.f,0.f,0.f};
  f4 acc[2][8];
  #pragma unroll
  for(int a=0;a<2;a++){
    #pragma unroll
    for(int b=0;b<8;b++) acc[a][b] = zero4;
  }
  int nks = K >> 5;
  for(int ks=0; ks<nks; ks++){
    __syncthreads();
    #pragma unroll
    for(int i=0;i<2;i++){
      int idx = tid + i*256;
      int r = idx>>2, c8 = (idx&3)*8;
      int row = rbase + r; row = row < M ? row : M-1;
      *(bf8*)(At + r*40 + c8) = ld8f(A + (size_t)row*K + ks*32 + c8);
    }
    __syncthreads();
    bf8 bfr[8];
    #pragma unroll
    for(int cf=0;cf<8;cf++)
      bfr[cf] = *(const bf8*)(Wf + ((size_t)((ks*8+cf)*64 + lane))*8);
    #pragma unroll
    for(int rf=0;rf<2;rf++){
      bf8 a = *(const bf8*)(At + (wv*32 + rf*16 + l16)*40 + quad*8);
      #pragma unroll
      for(int cf=0;cf<8;cf++)
        acc[rf][cf] = __builtin_amdgcn_mfma_f32_16x16x32_bf16(a, bfr[cf], acc[rf][cf], 0,0,0);
    }
  }
  #pragma unroll
  for(int rf=0;rf<2;rf++){
    #pragma unroll
    for(int cf=0;cf<8;cf++){
      int col = cf*16 + l16;
      float bv = bias[col];
      #pragma unroll
      for(int r=0;r<4;r++){
        int row = wv*32 + rf*16 + quad*4 + r;
        Ot[row*136 + col] = f2bf(fin(acc[rf][cf][r] + bv));
      }
    }
  }
  __syncthreads();
  #pragma unroll
  for(int i=0;i<8;i++){
    int idx = tid + i*256;
    int r = idx>>4, c8 = (idx&15)*8;
    int row = rbase + r;
    if(row < M){
      bf8 o = *(const bf8*)(Ot + r*136 + c8);
      if(obf){
        *(bf8*)((u16*)C + (size_t)row*128 + c8) = o;
      } else {
        float* Cf = (float*)C + (size_t)row*128 + c8;
        float4 p0, p1;
        p0.x=bf2f((u16)o[0]); p0.y=bf2f((u16)o[1]); p0.z=bf2f((u16)o[2]); p0.w=bf2f((u16)o[3]);
        p1.x=bf2f((u16)o[4]); p1.y=bf2f((u16)o[5]); p1.z=bf2f((u16)o[6]); p1.w=bf2f((u16)o[7]);
        *(float4*)Cf = p0; *(float4*)(Cf+4) = p1;
      }
    }
  }
}

// h rows in CSR-permuted order for nodes [n0,n1):
// h[r-p0] = [x[dst(e)] | x[src(e)] | ea[e]] @ Bfused + biasH,  e = eids[r], r in [p0,p1)
// x is f32 [NN,128]; ea is bf16 [NE,128]
__global__ __launch_bounds__(256) void k_gemm_h_perm(const float* __restrict__ x, const u16* __restrict__ ea,
    const int* __restrict__ ei, const int* __restrict__ eids, const int* __restrict__ rowptr,
    int n0, int n1, const u16* __restrict__ Wf, const float* __restrict__ biasH,
    u16* __restrict__ hperm)
{
  __shared__ __align__(16) u16 At[128*40];
  __shared__ __align__(16) u16 Ot[128*136];
  __shared__ int sD[128], sS[128], sE[128];
  int p0 = rowptr[n0], p1 = rowptr[n1];
  int rbase = p0 + blockIdx.x*128;
  if(rbase >= p1) return;                 // uniform across block
  int tid = threadIdx.x, lane = tid&63, wv = tid>>6;
  int quad = lane>>4, l16 = lane&15;
  if(tid < 128){
    int pos = rbase + tid; if(pos >= p1) pos = p1 - 1;
    unsigned e = (unsigned)eids[pos]; if(e >= NE) e = 0;
    sE[tid] = (int)e;
    unsigned s = (unsigned)ei[e];    if(s >= NN) s = 0;
    unsigned d = (unsigned)ei[NE+e]; if(d >= NN) d = 0;
    sS[tid] = (int)s; sD[tid] = (int)d;
  }
  f4 zero4 = {0.f,0.f,0.f,0.f};
  f4 acc[2][8];
  #pragma unroll
  for(int a=0;a<2;a++){
    #pragma unroll
    for(int b=0;b<8;b++) acc[a][b] = zero4;
  }
  for(int ks=0; ks<12; ks++){
    __syncthreads();
    #pragma unroll
    for(int i=0;i<2;i++){
      int idx = tid + i*256;
      int r = idx>>2, c8 = (idx&3)*8;
      int off = (ks&3)*32 + c8;
      int reg = ks>>2;
      bf8 v;
      if(reg==0)      v = ld8f(x + (size_t)sD[r]*128 + off);   // x_i = x[dst]
      else if(reg==1) v = ld8f(x + (size_t)sS[r]*128 + off);   // x_j = x[src]
      else            v = *(const bf8*)(ea + (size_t)sE[r]*128 + off);
      *(bf8*)(At + r*40 + c8) = v;
    }
    __syncthreads();
    bf8 bfr[8];
    #pragma unroll
    for(int cf=0;cf<8;cf++)
      bfr[cf] = *(const bf8*)(Wf + ((size_t)((ks*8+cf)*64 + lane))*8);
    #pragma unroll
    for(int rf=0;rf<2;rf++){
      bf8 a = *(const bf8*)(At + (wv*32 + rf*16 + l16)*40 + quad*8);
      #pragma unroll
      for(int cf=0;cf<8;cf++)
        acc[rf][cf] = __builtin_amdgcn_mfma_f32_16x16x32_bf16(a, bfr[cf], acc[rf][cf], 0,0,0);
    }
  }
  #pragma unroll
  for(int rf=0;rf<2;rf++){
    #pragma unroll
    for(int cf=0;cf<8;cf++){
      int col = cf*16 + l16;
      float bv = biasH[col];
      #pragma unroll
      for(int r=0;r<4;r++){
        int row = wv*32 + rf*16 + quad*4 + r;
        Ot[row*136 + col] = f2bf(fin(acc[rf][cf][r] + bv));
      }
    }
  }
  __syncthreads();
  #pragma unroll
  for(int i=0;i<8;i++){
    int idx = tid + i*256;
    int r = idx>>4, c8 = (idx&15)*8;
    int gr = rbase + r;                       // global CSR position
    int lr = gr - p0;                         // chunk-local row
    if(gr < p1 && lr < HCAP)
      *(bf8*)(hperm + (size_t)lr*128 + c8) = *(const bf8*)(Ot + r*136 + c8);
  }
}

// per-node aggregation over CSR-contiguous h rows: mean|min|max|std -> agg [N,512] bf16
__global__ __launch_bounds__(128) void k_agg_csr(const u16* __restrict__ h, const int* __restrict__ rowptr,
     int n0, u16* __restrict__ agg)
{
  int n = n0 + blockIdx.x, c = threadIdx.x;
  int p0 = rowptr[n0];
  int s0 = rowptr[n], s1e = rowptr[n+1];
  float s1 = 0.f, s2 = 0.f, mn = 1e30f, mx = -1e30f;
  for(int i=s0; i<s1e; i++){
    int lr = i - p0; if(lr >= HCAP) break;
    float v = bf2f(h[(size_t)lr*128 + c]);
    s1 += v; s2 += v*v;
    mn = fminf(mn, v); mx = fmaxf(mx, v);
  }
  int d = s1e - s0;
  float degc = (float)(d > 1 ? d : 1);
  float mean = s1/degc;
  float var = s2/degc - mean*mean; var = var > 0.f ? var : 0.f;
  float sd = sqrtf(var + 1e-5f);
  if(d == 0){ mn = 0.f; mx = 0.f; }
  size_t base = (size_t)n*512 + c;
  agg[base      ] = f2bf(fin(mean));
  agg[base + 128] = f2bf(fin(mn));
  agg[base + 256] = f2bf(fin(mx));
  agg[base + 384] = f2bf(fin(sd));
}

// out2 = ([x | agg | amp*agg | att*agg] @ post_w + post_b) @ lin_w + lin_b   (fp32 out)
// x f32, agg bf16
__global__ __launch_bounds__(256) void k_gemm_post(const float* __restrict__ x, const u16* __restrict__ agg,
   const float* __restrict__ amp, const float* __restrict__ att,
   const u16* __restrict__ Wf1, const float* __restrict__ pb,
   const u16* __restrict__ Wf2, const float* __restrict__ lb,
   float* __restrict__ out2)
{
  __shared__ __align__(16) u16 At[128*40];
  __shared__ __align__(16) u16 Ot[128*136];
  __shared__ float sA[128], sT[128];
  int tid = threadIdx.x, lane = tid&63, wv = tid>>6;
  int quad = lane>>4, l16 = lane&15;
  int nbase = blockIdx.x*128;
  if(tid < 128){ int n = nbase + tid; n = n < NN ? n : NN-1; sA[tid] = amp[n]; sT[tid] = att[n]; }
  f4 zero4 = {0.f,0.f,0.f,0.f};
  f4 acc[2][8];
  #pragma unroll
  for(int a=0;a<2;a++){
    #pragma unroll
    for(int b=0;b<8;b++) acc[a][b] = zero4;
  }
  for(int ks=0; ks<52; ks++){
    __syncthreads();
    #pragma unroll
    for(int i=0;i<2;i++){
      int idx = tid + i*256;
      int r = idx>>2, c8 = (idx&3)*8;
      int n = nbase + r; n = n < NN ? n : NN-1;
      int vc = ks*32 + c8;
      if(ks < 4){
        *(bf8*)(At + r*40 + c8) = ld8f(x + (size_t)n*128 + vc);
      } else if(ks < 20){
        *(bf8*)(At + r*40 + c8) = *(const bf8*)(agg + (size_t)n*512 + (vc-128));
      } else {
        float sc; int ac;
        if(ks < 36){ sc = sA[r]; ac = vc - 640; }
        else       { sc = sT[r]; ac = vc - 1152; }
        bf8 v = *(const bf8*)(agg + (size_t)n*512 + ac);
        bf8 o;
        #pragma unroll
        for(int jj=0;jj<8;jj++) o[jj] = (short)f2bf(sc * bf2f((u16)v[jj]));
        *(bf8*)(At + r*40 + c8) = o;
      }
    }
    __syncthreads();
    bf8 bfr[8];
    #pragma unroll
    for(int cf=0;cf<8;cf++)
      bfr[cf] = *(const bf8*)(Wf1 + ((size_t)((ks*8+cf)*64 + lane))*8);
    #pragma unroll
    for(int rf=0;rf<2;rf++){
      bf8 a = *(const bf8*)(At + (wv*32 + rf*16 + l16)*40 + quad*8);
      #pragma unroll
      for(int cf=0;cf<8;cf++)
        acc[rf][cf] = __builtin_amdgcn_mfma_f32_16x16x32_bf16(a, bfr[cf], acc[rf][cf], 0,0,0);
    }
  }
  // + post_b -> bf16 tile
  #pragma unroll
  for(int rf=0;rf<2;rf++){
    #pragma unroll
    for(int cf=0;cf<8;cf++){
      int col = cf*16 + l16;
      float bv = pb[col];
      #pragma unroll
      for(int r=0;r<4;r++){
        int row = wv*32 + rf*16 + quad*4 + r;
        Ot[row*136 + col] = f2bf(fin(acc[rf][cf][r] + bv));
      }
    }
  }
  __syncthreads();
  // fused lin: K=128
  f4 acc2[2][8];
  #pragma unroll
  for(int a=0;a<2;a++){
    #pragma unroll
    for(int b=0;b<8;b++) acc2[a][b] = zero4;
  }
  for(int ks=0; ks<4; ks++){
    bf8 bfr[8];
    #pragma unroll
    for(int cf=0;cf<8;cf++)
      bfr[cf] = *(const bf8*)(Wf2 + ((size_t)((ks*8+cf)*64 + lane))*8);
    #pragma unroll
    for(int rf=0;rf<2;rf++){
      bf8 a = *(const bf8*)(Ot + (wv*32 + rf*16 + l16)*136 + ks*32 + quad*8);
      #pragma unroll
      for(int cf=0;cf<8;cf++)
        acc2[rf][cf] = __builtin_amdgcn_mfma_f32_16x16x32_bf16(a, bfr[cf], acc2[rf][cf], 0,0,0);
    }
  }
  #pragma unroll
  for(int rf=0;rf<2;rf++){
    #pragma unroll
    for(int cf=0;cf<8;cf++){
      int col = cf*16 + l16;
      float bv = lb[col];
      #pragma unroll
      for(int r=0;r<4;r++){
        int row = nbase + wv*32 + rf*16 + quad*4 + r;
        if(row < NN) out2[(size_t)row*128 + col] = fin(acc2[rf][cf][r] + bv);
      }
    }
  }
}

__global__ __launch_bounds__(128) void k_bnstats(const float* __restrict__ out2, float* __restrict__ S){
  int c = threadIdx.x;
  float s1 = 0.f, s2 = 0.f;
  for(int r = blockIdx.x; r < NN; r += gridDim.x){
    float v = out2[(size_t)r*128 + c];
    s1 += v; s2 += v*v;
  }
  atomicAdd(&S[c], s1);
  atomicAdd(&S[128+c], s2);
}

// x (f32, in d_out) = (x + relu(bn))/2
__global__ __launch_bounds__(256) void k_xupd(const float* __restrict__ out2, const float* __restrict__ S,
    const float* __restrict__ g, const float* __restrict__ b, float* __restrict__ x)
{
  int i = blockIdx.x*256 + threadIdx.x;
  int c = i & 127;
  const float inv = 1.0f/(float)NN;
  float mu = fin(S[c]*inv);
  float var = fin(S[128+c]*inv - mu*mu); var = var > 0.f ? var : 0.f;
  float rs = rsqrtf(var + 1e-5f);
  float bn = g[c]*(out2[i]-mu)*rs + b[c];
  bn = bn > 0.f ? bn : 0.f;
  x[i] = fin((x[i] + bn)*0.5f);
}

// ea += 0.5*( relu([x[src]|x[dst]|ea]@W1 + b1) @ W2 + b2 );  x f32, ea bf16
__global__ __launch_bounds__(256) void k_gemm_emlp(const float* __restrict__ x, u16* __restrict__ ea,
   const int* __restrict__ ei, const u16* __restrict__ Wf1, const float* __restrict__ b1,
   const u16* __restrict__ Wf2, const float* __restrict__ b2)
{
  __shared__ __align__(16) u16 At[128*40];
  __shared__ __align__(16) u16 Ot[128*136];
  __shared__ int sS[128], sD[128];
  int tid = threadIdx.x, lane = tid&63, wv = tid>>6;
  int quad = lane>>4, l16 = lane&15;
  int ebase = blockIdx.x*128;
  if(tid < 128){
    unsigned s = (unsigned)ei[ebase + tid];      if(s >= NN) s = 0;
    unsigned d = (unsigned)ei[NE + ebase + tid]; if(d >= NN) d = 0;
    sS[tid] = (int)s; sD[tid] = (int)d;
  }
  f4 zero4 = {0.f,0.f,0.f,0.f};
  f4 acc[2][8];
  #pragma unroll
  for(int a=0;a<2;a++){
    #pragma unroll
    for(int b=0;b<8;b++) acc[a][b] = zero4;
  }
  for(int ks=0; ks<12; ks++){
    __syncthreads();
    #pragma unroll
    for(int i=0;i<2;i++){
      int idx = tid + i*256;
      int r = idx>>2, c8 = (idx&3)*8;
      int off = (ks&3)*32 + c8;
      int reg = ks>>2;
      bf8 v;
      if(reg==0)      v = ld8f(x + (size_t)sS[r]*128 + off);   // x[src] first here
      else if(reg==1) v = ld8f(x + (size_t)sD[r]*128 + off);
      else            v = *(const bf8*)(ea + (size_t)(ebase+r)*128 + off);
      *(bf8*)(At + r*40 + c8) = v;
    }
    __syncthreads();
    bf8 bfr[8];
    #pragma unroll
    for(int cf=0;cf<8;cf++)
      bfr[cf] = *(const bf8*)(Wf1 + ((size_t)((ks*8+cf)*64 + lane))*8);
    #pragma unroll
    for(int rf=0;rf<2;rf++){
      bf8 a = *(const bf8*)(At + (wv*32 + rf*16 + l16)*40 + quad*8);
      #pragma unroll
      for(int cf=0;cf<8;cf++)
        acc[rf][cf] = __builtin_amdgcn_mfma_f32_16x16x32_bf16(a, bfr[cf], acc[rf][cf], 0,0,0);
    }
  }
  // relu(+b1) -> Ot
  #pragma unroll
  for(int rf=0;rf<2;rf++){
    #pragma unroll
    for(int cf=0;cf<8;cf++){
      int col = cf*16 + l16;
      float bv = b1[col];
      #pragma unroll
      for(int r=0;r<4;r++){
        int row = wv*32 + rf*16 + quad*4 + r;
        float v = acc[rf][cf][r] + bv;
        Ot[row*136 + col] = f2bf(v > 0.f ? fin(v) : 0.f);
      }
    }
  }
  __syncthreads();
  f4 acc2[2][8];
  #pragma unroll
  for(int a=0;a<2;a++){
    #pragma unroll
    for(int b=0;b<8;b++) acc2[a][b] = zero4;
  }
  for(int ks=0; ks<4; ks++){
    bf8 bfr[8];
    #pragma unroll
    for(int cf=0;cf<8;cf++)
      bfr[cf] = *(const bf8*)(Wf2 + ((size_t)((ks*8+cf)*64 + lane))*8);
    #pragma unroll
    for(int rf=0;rf<2;rf++){
      bf8 a = *(const bf8*)(Ot + (wv*32 + rf*16 + l16)*136 + ks*32 + quad*8);
      #pragma unroll
      for(int cf=0;cf<8;cf++)
        acc2[rf][cf] = __builtin_amdgcn_mfma_f32_16x16x32_bf16(a, bfr[cf], acc2[rf][cf], 0,0,0);
    }
  }
  __syncthreads();
  #pragma unroll
  for(int rf=0;rf<2;rf++){
    #pragma unroll
    for(int cf=0;cf<8;cf++){
      int col = cf*16 + l16;
      float bv = b2[col];
      #pragma unroll
      for(int r=0;r<4;r++){
        int row = wv*32 + rf*16 + quad*4 + r;
        Ot[row*136 + col] = f2bf(0.5f*(acc2[rf][cf][r] + bv));
      }
    }
  }
  __syncthreads();
  #pragma unroll
  for(int i=0;i<8;i++){
    int idx = tid + i*256;
    int r = idx>>4, c8 = (idx&15)*8;
    size_t gidx = (size_t)(ebase+r)*128 + c8;
    bf8 e = *(const bf8*)(ea + gidx);
    bf8 o = *(const bf8*)(Ot + r*136 + c8);
    bf8 res;
    #pragma unroll
    for(int jj=0;jj<8;jj++) res[jj] = (short)f2bf(fin(bf2f((u16)e[jj]) + bf2f((u16)o[jj])));
    *(bf8*)(ea + gidx) = res;
  }
}

// ---------------- launcher ----------------
extern "C" void kernel_launch(void* const* d_in, const int* in_sizes, int n_in,
                              void* d_out, int out_size, void* d_ws, size_t ws_size,
                              hipStream_t stream)
{
  const float* x_in   = (const float*)d_in[0];
  const int*   ei     = (const int*)d_in[1];
  const float* eatt   = (const float*)d_in[2];
  const float* patt   = (const float*)d_in[4];
  const float* natt   = (const float*)d_in[6];
  const float* w_node = (const float*)d_in[8];
  const float* b_node = (const float*)d_in[9];
  const float* w_edge = (const float*)d_in[10];
  const float* b_edge = (const float*)d_in[11];
  const float* eenc_w = (const float*)d_in[12];
  const float* eenc_b = (const float*)d_in[13];
  const float* pre_w  = (const float*)d_in[14];
  const float* pre_b  = (const float*)d_in[15];
  const float* post_w = (const float*)d_in[16];
  const float* post_b = (const float*)d_in[17];
  const float* lin_w  = (const float*)d_in[18];
  const float* lin_b  = (const float*)d_in[19];
  const float* emlp_w1= (const float*)d_in[20];
  const float* emlp_b1= (const float*)d_in[21];
  const float* emlp_w2= (const float*)d_in[22];
  const float* emlp_b2= (const float*)d_in[23];
  const float* bn_g   = (const float*)d_in[24];
  const float* bn_b   = (const float*)d_in[25];

  float* xcur  = (float*)d_out;                   // x (f32) lives in d_out
  float* pos_o = xcur + (size_t)NN*HD;
  float* neg_o = pos_o + (size_t)NEP*HD;

  // ---- workspace layout (no aliasing; ~237 MB) ----
  char* p = (char*)d_ws;
  auto alloc = [&](size_t b)->void*{ void* r = (void*)p; p += (b + 255) & ~(size_t)255; return r; };
  u16*   ea     = (u16*)  alloc((size_t)NE*HD*2);      // 102.4 MB (internal bf16)
  u16*   hperm  = (u16*)  alloc((size_t)HCAP*HD*2);    //  53.8 MB
  u16*   agg    = (u16*)  alloc((size_t)NN*4*HD*2);    //  51.2 MB
  float* out2   = (float*)alloc((size_t)NN*HD*4);      //  25.6 MB
  int*   deg    = (int*)  alloc((size_t)NN*4);
  int*   cursor = (int*)  alloc((size_t)NN*4);
  int*   rowptr = (int*)  alloc((size_t)(NN+1)*4);
  int*   eids   = (int*)  alloc((size_t)NE*4);
  float* amp    = (float*)alloc((size_t)NN*4);
  float* att    = (float*)alloc((size_t)NN*4);
  float* adlbuf = (float*)alloc(256);
  float* biasH  = (float*)alloc((size_t)NL*HD*4);
  u16*   BpreP  = (u16*)  alloc((size_t)NL*384*HD*2);
  u16*   f_node = (u16*)  alloc((size_t)64*HD*2);
  u16*   f_edge = (u16*)  alloc((size_t)32*HD*2);
  u16*   f_pre  = (u16*)  alloc((size_t)NL*384*HD*2);
  u16*   f_e1   = (u16*)  alloc((size_t)NL*384*HD*2);
  u16*   f_e2   = (u16*)  alloc((size_t)NL*HD*HD*2);
  u16*   f_lin  = (u16*)  alloc((size_t)NL*HD*HD*2);
  u16*   f_post = (u16*)  alloc((size_t)NL*1664*HD*2);
  float* S      = (float*)alloc((size_t)2*HD*4);

  k_zero    <<<(NN+255)/256, 256, 0, stream>>>(deg, NN);
  k_zero    <<<(NN+255)/256, 256, 0, stream>>>(cursor, NN);
  k_deg     <<<(NE+255)/256, 256, 0, stream>>>(ei, deg);
  k_adl     <<<1, 1024, 0, stream>>>(deg, adlbuf);
  k_scan    <<<1, 1024, 0, stream>>>(deg, rowptr);
  k_nodeprep<<<(NN+255)/256, 256, 0, stream>>>(deg, adlbuf, amp, att);
  k_fill    <<<(NE+255)/256, 256, 0, stream>>>(ei, rowptr, cursor, eids);
  k_fold_pre<<<NL, 256, 0, stream>>>(eenc_w, eenc_b, pre_w, pre_b, BpreP, biasH);

  FragJobs J;
  int u = 0, ji = 0;
  auto addjob = [&](const void* s, u16* d, int K, int f32){
    J.src[ji] = s; J.dst[ji] = d; J.isf32[ji] = f32; u += K*16; J.end[ji] = u; ji++; };
  addjob(w_node, f_node, 64, 1);
  addjob(w_edge, f_edge, 32, 1);
  for(int l=0;l<NL;l++) addjob(BpreP   + l*384*HD, f_pre  + l*384*HD, 384, 0);
  for(int l=0;l<NL;l++) addjob(emlp_w1 + l*384*HD, f_e1   + l*384*HD, 384, 1);
  for(int l=0;l<NL;l++) addjob(emlp_w2 + l*HD*HD,  f_e2   + l*HD*HD,  128, 1);
  for(int l=0;l<NL;l++) addjob(lin_w   + l*HD*HD,  f_lin  + l*HD*HD,  128, 1);
  for(int l=0;l<NL;l++) addjob(post_w  + l*1664*HD,f_post + l*1664*HD,1664, 1);
  k_fragB<<<(u+255)/256, 256, 0, stream>>>(J);

  k_gemm_rm<<<(NN+127)/128, 256, 0, stream>>>(x_in, f_node, b_node, xcur, NN, FD, 0);
  k_gemm_rm<<<NE/128,        256, 0, stream>>>(eatt, f_edge, b_edge, ea,    NE, EDD, 1);
  k_gemm_rm<<<(NEP+127)/128, 256, 0, stream>>>(patt, f_edge, b_edge, pos_o, NEP, EDD, 0);
  k_gemm_rm<<<(NEP+127)/128, 256, 0, stream>>>(natt, f_edge, b_edge, neg_o, NEP, EDD, 0);

  const int NHALF = NN/2;   // 25000
  for(int l=0; l<NL; l++){
    for(int c=0; c<2; c++){
      int n0 = c*NHALF, n1 = (c==1) ? NN : (c+1)*NHALF;
      k_gemm_h_perm<<<NE/128, 256, 0, stream>>>(xcur, ea, ei, eids, rowptr, n0, n1,
                     f_pre + l*384*HD, biasH + l*HD, hperm);
      k_agg_csr    <<<n1-n0, 128, 0, stream>>>(hperm, rowptr, n0, agg);
    }
    k_gemm_post<<<(NN+127)/128, 256, 0, stream>>>(xcur, agg, amp, att,
                  f_post + l*1664*HD, post_b + l*HD, f_lin + l*HD*HD, lin_b + l*HD, out2);
    k_zero     <<<1, 256, 0, stream>>>((int*)S, 2*HD);
    k_bnstats  <<<512, 128, 0, stream>>>(out2, S);
    k_xupd     <<<(NN*HD)/256, 256, 0, stream>>>(out2, S, bn_g + l*HD, bn_b + l*HD, xcur);
    k_gemm_emlp<<<NE/128, 256, 0, stream>>>(xcur, ea, ei, f_e1 + l*384*HD, emlp_b1 + l*HD,
                  f_e2 + l*HD*HD, emlp_b2 + l*HD);
  }
}

// Round 6
// 1307.794 us; speedup vs baseline: 1.2047x; 1.2047x over previous
//
#include <hip/hip_runtime.h>
#include <math.h>

#define NN 50000
#define NE 400000
#define NEP 40000
#define FD 64
#define EDD 32
#define HD 128
#define NL 2
#define HCAP 210000   // per-chunk h-row capacity (chunk mean 200k, sigma ~316)

typedef unsigned short u16;
typedef __attribute__((ext_vector_type(8))) short bf8;   // 8 x bf16 = 16B
typedef __attribute__((ext_vector_type(4))) float f4;    // MFMA accumulator

__device__ __forceinline__ float bf2f(u16 u){ return __uint_as_float(((unsigned)u)<<16); }
__device__ __forceinline__ u16 f2bf(float f){
  unsigned u = __float_as_uint(f);
  u += 0x7FFFu + ((u>>16)&1u);           // RNE
  return (u16)(u>>16);
}
// squash NaN/Inf to 0 (bit-level: robust under any fp flags)
__device__ __forceinline__ float fin(float f){
  unsigned u = __float_as_uint(f);
  return ((u & 0x7F800000u) == 0x7F800000u) ? 0.f : f;
}
// load 8 f32, convert to 8 bf16
__device__ __forceinline__ bf8 ld8f(const float* __restrict__ p){
  float4 a = *(const float4*)p;
  float4 b = *(const float4*)(p+4);
  bf8 o;
  o[0]=(short)f2bf(a.x); o[1]=(short)f2bf(a.y); o[2]=(short)f2bf(a.z); o[3]=(short)f2bf(a.w);
  o[4]=(short)f2bf(b.x); o[5]=(short)f2bf(b.y); o[6]=(short)f2bf(b.z); o[7]=(short)f2bf(b.w);
  return o;
}

// ---------------- setup kernels ----------------
__global__ __launch_bounds__(256) void k_zero(int* __restrict__ p, int n){
  int i = blockIdx.x*256 + threadIdx.x;
  if(i < n) p[i] = 0;
}

__global__ __launch_bounds__(256) void k_deg(const int* __restrict__ ei, int* __restrict__ deg){
  int e = blockIdx.x*256 + threadIdx.x;
  if(e < NE){
    unsigned d = (unsigned)ei[NE+e]; if(d >= NN) d = 0;
    atomicAdd(&deg[d], 1);
  }
}

// avg_deg_log = mean over nodes of log(deg+1)  (recomputed on-device; ignores input scalar)
__global__ __launch_bounds__(1024) void k_adl(const int* __restrict__ deg, float* __restrict__ adlbuf){
  __shared__ float sums[1024];
  int t = threadIdx.x;
  float s = 0.f;
  for(int n = t; n < NN; n += 1024) s += logf((float)deg[n] + 1.0f);
  sums[t] = s;
  __syncthreads();
  for(int off = 512; off > 0; off >>= 1){
    if(t < off) sums[t] += sums[t+off];
    __syncthreads();
  }
  if(t == 0){
    float adl = sums[0] / (float)NN;
    if(!(adl > 1e-6f)) adl = 1.0f;
    adlbuf[0] = adl;
  }
}

__global__ __launch_bounds__(1024) void k_scan(const int* __restrict__ deg, int* __restrict__ rowptr){
  __shared__ int sums[1024];
  int t = threadIdx.x;
  const int CH = (NN + 1023)/1024;   // 49
  int st = t*CH;
  int local = 0;
  for(int i=0;i<CH;i++){ int n = st+i; if(n<NN) local += deg[n]; }
  sums[t] = local;
  __syncthreads();
  for(int off=1; off<1024; off<<=1){
    int v = sums[t];
    int add = (t>=off) ? sums[t-off] : 0;
    __syncthreads();
    sums[t] = v + add;
    __syncthreads();
  }
  int run = sums[t] - local;          // exclusive prefix
  for(int i=0;i<CH;i++){ int n = st+i; if(n<NN){ rowptr[n] = run; run += deg[n]; } }
  if(t==0) rowptr[NN] = NE;
}

__global__ __launch_bounds__(256) void k_nodeprep(const int* __restrict__ deg, const float* __restrict__ adlbuf,
                                                  float* __restrict__ amp, float* __restrict__ att){
  int n = blockIdx.x*256 + threadIdx.x;
  if(n >= NN) return;
  float adl = adlbuf[0];
  int d = deg[n]; if(d < 1) d = 1;
  float lg = logf((float)d + 1.0f);
  float a1 = lg/adl, a2 = adl/lg;
  a1 = fminf(fmaxf(a1, 1e-6f), 1e4f);
  a2 = fminf(fmaxf(a2, 1e-6f), 1e4f);
  amp[n] = a1;
  att[n] = a2;
}

__global__ __launch_bounds__(256) void k_fill(const int* __restrict__ ei, const int* __restrict__ rowptr,
                                              int* __restrict__ cursor, int* __restrict__ eids){
  int e = blockIdx.x*256 + threadIdx.x;
  if(e >= NE) return;
  unsigned d = (unsigned)ei[NE+e]; if(d >= NN) d = 0;
  int c = atomicAdd(&cursor[d], 1);
  eids[rowptr[d] + c] = e;
}

// PARALLEL fold of eenc into pre (was the 275us serial hotspot: grid=2).
// grid = NL*129 blocks x 128 threads: block k<128 computes row k of eenc_w@pre_w[256:384];
// block k==128 computes biasH = eenc_b@pre_w[256:] + pre_b.
__global__ __launch_bounds__(128) void k_fold_row(const float* __restrict__ eenc_w, const float* __restrict__ eenc_b,
                   const float* __restrict__ pre_w, const float* __restrict__ pre_b,
                   u16* __restrict__ Bp, float* __restrict__ biasH){
  int l = blockIdx.x / 129;
  int k = blockIdx.x % 129;
  int c = threadIdx.x;                  // 128, coalesced over PW columns
  const float* EW = eenc_w + l*HD*HD;
  const float* PW = pre_w  + l*384*HD;
  if(k < 128){
    float s = 0.f;
    #pragma unroll 4
    for(int j=0;j<HD;j++) s += EW[k*HD+j] * PW[(256+j)*HD + c];
    Bp[l*384*HD + (256+k)*HD + c] = f2bf(s);
  } else {
    float s = pre_b[l*HD + c];
    #pragma unroll 4
    for(int j=0;j<HD;j++) s += eenc_b[l*HD+j] * PW[(256+j)*HD + c];
    biasH[l*HD + c] = s;
  }
}
// copy pre_w[0:256] (f32) -> Bp[0:256] (bf16), both layers: NL*256*128 elems
__global__ __launch_bounds__(256) void k_fold_copy(const float* __restrict__ pre_w, u16* __restrict__ Bp){
  int i = blockIdx.x*256 + threadIdx.x;
  if(i >= NL*256*HD) return;
  int l = i / (256*HD);
  int r = i - l*(256*HD);
  Bp[l*384*HD + r] = f2bf(pre_w[l*384*HD + r]);
}

// repack weight matrices [K][128] into per-(kstep,colfrag,lane) contiguous MFMA B-fragments.
// per-job flag: src is f32 (1) or bf16 (0)
#define NJOBS 12
struct FragJobs {
  const void* src[NJOBS];
  u16* dst[NJOBS];
  int end[NJOBS];   // cumulative unit counts; units per job = K*16
  int isf32[NJOBS];
};
__global__ __launch_bounds__(256) void k_fragB(FragJobs J){
  int u = blockIdx.x*256 + threadIdx.x;
  int j = 0, start = 0;
  while(j < NJOBS && u >= J.end[j]){ start = J.end[j]; j++; }
  if(j >= NJOBS) return;
  int lu = u - start;
  int lane = lu & 63, cf = (lu>>6)&7, ks = lu>>9;
  u16* d = J.dst[j];
  #pragma unroll
  for(int i=0;i<8;i++){
    size_t si = (size_t)(ks*32 + (lane>>4)*8 + i)*HD + cf*16 + (lane&15);
    u16 v = J.isf32[j] ? f2bf(((const float*)J.src[j])[si]) : ((const u16*)J.src[j])[si];
    d[((size_t)((ks*8+cf)*64 + lane))*8 + i] = v;
  }
}

// ---------------- GEMM kernels ----------------
// A [M,K] f32 row-major @ Wfrag -> C [M,128]; obf=1: bf16 out, obf=0: f32 out
__global__ __launch_bounds__(256) void k_gemm_rm(const float* __restrict__ A, const u16* __restrict__ Wf,
      const float* __restrict__ bias, void* __restrict__ C, int M, int K, int obf)
{
  __shared__ __align__(16) u16 At[128*40];
  __shared__ __align__(16) u16 Ot[128*136];
  int tid = threadIdx.x, lane = tid&63, wv = tid>>6;
  int quad = lane>>4, l16 = lane&15;
  int rbase = blockIdx.x*128;
  f4 zero4 = {0.f,0.f,0.f,0.f};
  f4 acc[2][8];
  #pragma unroll
  for(int a=0;a<2;a++){
    #pragma unroll
    for(int b=0;b<8;b++) acc[a][b] = zero4;
  }
  int nks = K >> 5;
  for(int ks=0; ks<nks; ks++){
    __syncthreads();
    #pragma unroll
    for(int i=0;i<2;i++){
      int idx = tid + i*256;
      int r = idx>>2, c8 = (idx&3)*8;
      int row = rbase + r; row = row < M ? row : M-1;
      *(bf8*)(At + r*40 + c8) = ld8f(A + (size_t)row*K + ks*32 + c8);
    }
    __syncthreads();
    bf8 bfr[8];
    #pragma unroll
    for(int cf=0;cf<8;cf++)
      bfr[cf] = *(const bf8*)(Wf + ((size_t)((ks*8+cf)*64 + lane))*8);
    #pragma unroll
    for(int rf=0;rf<2;rf++){
      bf8 a = *(const bf8*)(At + (wv*32 + rf*16 + l16)*40 + quad*8);
      #pragma unroll
      for(int cf=0;cf<8;cf++)
        acc[rf][cf] = __builtin_amdgcn_mfma_f32_16x16x32_bf16(a, bfr[cf], acc[rf][cf], 0,0,0);
    }
  }
  #pragma unroll
  for(int rf=0;rf<2;rf++){
    #pragma unroll
    for(int cf=0;cf<8;cf++){
      int col = cf*16 + l16;
      float bv = bias[col];
      #pragma unroll
      for(int r=0;r<4;r++){
        int row = wv*32 + rf*16 + quad*4 + r;
        Ot[row*136 + col] = f2bf(fin(acc[rf][cf][r] + bv));
      }
    }
  }
  __syncthreads();
  #pragma unroll
  for(int i=0;i<8;i++){
    int idx = tid + i*256;
    int r = idx>>4, c8 = (idx&15)*8;
    int row = rbase + r;
    if(row < M){
      bf8 o = *(const bf8*)(Ot + r*136 + c8);
      if(obf){
        *(bf8*)((u16*)C + (size_t)row*128 + c8) = o;
      } else {
        float* Cf = (float*)C + (size_t)row*128 + c8;
        float4 p0, p1;
        p0.x=bf2f((u16)o[0]); p0.y=bf2f((u16)o[1]); p0.z=bf2f((u16)o[2]); p0.w=bf2f((u16)o[3]);
        p1.x=bf2f((u16)o[4]); p1.y=bf2f((u16)o[5]); p1.z=bf2f((u16)o[6]); p1.w=bf2f((u16)o[7]);
        *(float4*)Cf = p0; *(float4*)(Cf+4) = p1;
      }
    }
  }
}

// h rows in CSR-permuted order for nodes [n0,n1):
// h[r-p0] = [x[dst(e)] | x[src(e)] | ea[e]] @ Bfused + biasH,  e = eids[r], r in [p0,p1)
// x is f32 [NN,128]; ea is bf16 [NE,128]
__global__ __launch_bounds__(256) void k_gemm_h_perm(const float* __restrict__ x, const u16* __restrict__ ea,
    const int* __restrict__ ei, const int* __restrict__ eids, const int* __restrict__ rowptr,
    int n0, int n1, const u16* __restrict__ Wf, const float* __restrict__ biasH,
    u16* __restrict__ hperm)
{
  __shared__ __align__(16) u16 At[128*40];
  __shared__ __align__(16) u16 Ot[128*136];
  __shared__ int sD[128], sS[128], sE[128];
  int p0 = rowptr[n0], p1 = rowptr[n1];
  int rbase = p0 + blockIdx.x*128;
  if(rbase >= p1) return;                 // uniform across block
  int tid = threadIdx.x, lane = tid&63, wv = tid>>6;
  int quad = lane>>4, l16 = lane&15;
  if(tid < 128){
    int pos = rbase + tid; if(pos >= p1) pos = p1 - 1;
    unsigned e = (unsigned)eids[pos]; if(e >= NE) e = 0;
    sE[tid] = (int)e;
    unsigned s = (unsigned)ei[e];    if(s >= NN) s = 0;
    unsigned d = (unsigned)ei[NE+e]; if(d >= NN) d = 0;
    sS[tid] = (int)s; sD[tid] = (int)d;
  }
  f4 zero4 = {0.f,0.f,0.f,0.f};
  f4 acc[2][8];
  #pragma unroll
  for(int a=0;a<2;a++){
    #pragma unroll
    for(int b=0;b<8;b++) acc[a][b] = zero4;
  }
  for(int ks=0; ks<12; ks++){
    __syncthreads();
    #pragma unroll
    for(int i=0;i<2;i++){
      int idx = tid + i*256;
      int r = idx>>2, c8 = (idx&3)*8;
      int off = (ks&3)*32 + c8;
      int reg = ks>>2;
      bf8 v;
      if(reg==0)      v = ld8f(x + (size_t)sD[r]*128 + off);   // x_i = x[dst]
      else if(reg==1) v = ld8f(x + (size_t)sS[r]*128 + off);   // x_j = x[src]
      else            v = *(const bf8*)(ea + (size_t)sE[r]*128 + off);
      *(bf8*)(At + r*40 + c8) = v;
    }
    __syncthreads();
    bf8 bfr[8];
    #pragma unroll
    for(int cf=0;cf<8;cf++)
      bfr[cf] = *(const bf8*)(Wf + ((size_t)((ks*8+cf)*64 + lane))*8);
    #pragma unroll
    for(int rf=0;rf<2;rf++){
      bf8 a = *(const bf8*)(At + (wv*32 + rf*16 + l16)*40 + quad*8);
      #pragma unroll
      for(int cf=0;cf<8;cf++)
        acc[rf][cf] = __builtin_amdgcn_mfma_f32_16x16x32_bf16(a, bfr[cf], acc[rf][cf], 0,0,0);
    }
  }
  #pragma unroll
  for(int rf=0;rf<2;rf++){
    #pragma unroll
    for(int cf=0;cf<8;cf++){
      int col = cf*16 + l16;
      float bv = biasH[col];
      #pragma unroll
      for(int r=0;r<4;r++){
        int row = wv*32 + rf*16 + quad*4 + r;
        Ot[row*136 + col] = f2bf(fin(acc[rf][cf][r] + bv));
      }
    }
  }
  __syncthreads();
  #pragma unroll
  for(int i=0;i<8;i++){
    int idx = tid + i*256;
    int r = idx>>4, c8 = (idx&15)*8;
    int gr = rbase + r;                       // global CSR position
    int lr = gr - p0;                         // chunk-local row
    if(gr < p1 && lr < HCAP)
      *(bf8*)(hperm + (size_t)lr*128 + c8) = *(const bf8*)(Ot + r*136 + c8);
  }
}

// per-node aggregation over CSR-contiguous h rows: mean|min|max|std -> agg [N,512] bf16
__global__ __launch_bounds__(128) void k_agg_csr(const u16* __restrict__ h, const int* __restrict__ rowptr,
     int n0, u16* __restrict__ agg)
{
  int n = n0 + blockIdx.x, c = threadIdx.x;
  int p0 = rowptr[n0];
  int s0 = rowptr[n], s1e = rowptr[n+1];
  float s1 = 0.f, s2 = 0.f, mn = 1e30f, mx = -1e30f;
  for(int i=s0; i<s1e; i++){
    int lr = i - p0; if(lr >= HCAP) break;
    float v = bf2f(h[(size_t)lr*128 + c]);
    s1 += v; s2 += v*v;
    mn = fminf(mn, v); mx = fmaxf(mx, v);
  }
  int d = s1e - s0;
  float degc = (float)(d > 1 ? d : 1);
  float mean = s1/degc;
  float var = s2/degc - mean*mean; var = var > 0.f ? var : 0.f;
  float sd = sqrtf(var + 1e-5f);
  if(d == 0){ mn = 0.f; mx = 0.f; }
  size_t base = (size_t)n*512 + c;
  agg[base      ] = f2bf(fin(mean));
  agg[base + 128] = f2bf(fin(mn));
  agg[base + 256] = f2bf(fin(mx));
  agg[base + 384] = f2bf(fin(sd));
}

// out2 = ([x | agg | amp*agg | att*agg] @ post_w + post_b) @ lin_w + lin_b   (fp32 out)
// x f32, agg bf16
__global__ __launch_bounds__(256) void k_gemm_post(const float* __restrict__ x, const u16* __restrict__ agg,
   const float* __restrict__ amp, const float* __restrict__ att,
   const u16* __restrict__ Wf1, const float* __restrict__ pb,
   const u16* __restrict__ Wf2, const float* __restrict__ lb,
   float* __restrict__ out2)
{
  __shared__ __align__(16) u16 At[128*40];
  __shared__ __align__(16) u16 Ot[128*136];
  __shared__ float sA[128], sT[128];
  int tid = threadIdx.x, lane = tid&63, wv = tid>>6;
  int quad = lane>>4, l16 = lane&15;
  int nbase = blockIdx.x*128;
  if(tid < 128){ int n = nbase + tid; n = n < NN ? n : NN-1; sA[tid] = amp[n]; sT[tid] = att[n]; }
  f4 zero4 = {0.f,0.f,0.f,0.f};
  f4 acc[2][8];
  #pragma unroll
  for(int a=0;a<2;a++){
    #pragma unroll
    for(int b=0;b<8;b++) acc[a][b] = zero4;
  }
  for(int ks=0; ks<52; ks++){
    __syncthreads();
    #pragma unroll
    for(int i=0;i<2;i++){
      int idx = tid + i*256;
      int r = idx>>2, c8 = (idx&3)*8;
      int n = nbase + r; n = n < NN ? n : NN-1;
      int vc = ks*32 + c8;
      if(ks < 4){
        *(bf8*)(At + r*40 + c8) = ld8f(x + (size_t)n*128 + vc);
      } else if(ks < 20){
        *(bf8*)(At + r*40 + c8) = *(const bf8*)(agg + (size_t)n*512 + (vc-128));
      } else {
        float sc; int ac;
        if(ks < 36){ sc = sA[r]; ac = vc - 640; }
        else       { sc = sT[r]; ac = vc - 1152; }
        bf8 v = *(const bf8*)(agg + (size_t)n*512 + ac);
        bf8 o;
        #pragma unroll
        for(int jj=0;jj<8;jj++) o[jj] = (short)f2bf(sc * bf2f((u16)v[jj]));
        *(bf8*)(At + r*40 + c8) = o;
      }
    }
    __syncthreads();
    bf8 bfr[8];
    #pragma unroll
    for(int cf=0;cf<8;cf++)
      bfr[cf] = *(const bf8*)(Wf1 + ((size_t)((ks*8+cf)*64 + lane))*8);
    #pragma unroll
    for(int rf=0;rf<2;rf++){
      bf8 a = *(const bf8*)(At + (wv*32 + rf*16 + l16)*40 + quad*8);
      #pragma unroll
      for(int cf=0;cf<8;cf++)
        acc[rf][cf] = __builtin_amdgcn_mfma_f32_16x16x32_bf16(a, bfr[cf], acc[rf][cf], 0,0,0);
    }
  }
  // + post_b -> bf16 tile
  #pragma unroll
  for(int rf=0;rf<2;rf++){
    #pragma unroll
    for(int cf=0;cf<8;cf++){
      int col = cf*16 + l16;
      float bv = pb[col];
      #pragma unroll
      for(int r=0;r<4;r++){
        int row = wv*32 + rf*16 + quad*4 + r;
        Ot[row*136 + col] = f2bf(fin(acc[rf][cf][r] + bv));
      }
    }
  }
  __syncthreads();
  // fused lin: K=128
  f4 acc2[2][8];
  #pragma unroll
  for(int a=0;a<2;a++){
    #pragma unroll
    for(int b=0;b<8;b++) acc2[a][b] = zero4;
  }
  for(int ks=0; ks<4; ks++){
    bf8 bfr[8];
    #pragma unroll
    for(int cf=0;cf<8;cf++)
      bfr[cf] = *(const bf8*)(Wf2 + ((size_t)((ks*8+cf)*64 + lane))*8);
    #pragma unroll
    for(int rf=0;rf<2;rf++){
      bf8 a = *(const bf8*)(Ot + (wv*32 + rf*16 + l16)*136 + ks*32 + quad*8);
      #pragma unroll
      for(int cf=0;cf<8;cf++)
        acc2[rf][cf] = __builtin_amdgcn_mfma_f32_16x16x32_bf16(a, bfr[cf], acc2[rf][cf], 0,0,0);
    }
  }
  #pragma unroll
  for(int rf=0;rf<2;rf++){
    #pragma unroll
    for(int cf=0;cf<8;cf++){
      int col = cf*16 + l16;
      float bv = lb[col];
      #pragma unroll
      for(int r=0;r<4;r++){
        int row = nbase + wv*32 + rf*16 + quad*4 + r;
        if(row < NN) out2[(size_t)row*128 + col] = fin(acc2[rf][cf][r] + bv);
      }
    }
  }
}

__global__ __launch_bounds__(128) void k_bnstats(const float* __restrict__ out2, float* __restrict__ S){
  int c = threadIdx.x;
  float s1 = 0.f, s2 = 0.f;
  for(int r = blockIdx.x; r < NN; r += gridDim.x){
    float v = out2[(size_t)r*128 + c];
    s1 += v; s2 += v*v;
  }
  atomicAdd(&S[c], s1);
  atomicAdd(&S[128+c], s2);
}

// x (f32, in d_out) = (x + relu(bn))/2
__global__ __launch_bounds__(256) void k_xupd(const float* __restrict__ out2, const float* __restrict__ S,
    const float* __restrict__ g, const float* __restrict__ b, float* __restrict__ x)
{
  int i = blockIdx.x*256 + threadIdx.x;
  int c = i & 127;
  const float inv = 1.0f/(float)NN;
  float mu = fin(S[c]*inv);
  float var = fin(S[128+c]*inv - mu*mu); var = var > 0.f ? var : 0.f;
  float rs = rsqrtf(var + 1e-5f);
  float bn = g[c]*(out2[i]-mu)*rs + b[c];
  bn = bn > 0.f ? bn : 0.f;
  x[i] = fin((x[i] + bn)*0.5f);
}

// ea += 0.5*( relu([x[src]|x[dst]|ea]@W1 + b1) @ W2 + b2 );  x f32, ea bf16
__global__ __launch_bounds__(256) void k_gemm_emlp(const float* __restrict__ x, u16* __restrict__ ea,
   const int* __restrict__ ei, const u16* __restrict__ Wf1, const float* __restrict__ b1,
   const u16* __restrict__ Wf2, const float* __restrict__ b2)
{
  __shared__ __align__(16) u16 At[128*40];
  __shared__ __align__(16) u16 Ot[128*136];
  __shared__ int sS[128], sD[128];
  int tid = threadIdx.x, lane = tid&63, wv = tid>>6;
  int quad = lane>>4, l16 = lane&15;
  int ebase = blockIdx.x*128;
  if(tid < 128){
    unsigned s = (unsigned)ei[ebase + tid];      if(s >= NN) s = 0;
    unsigned d = (unsigned)ei[NE + ebase + tid]; if(d >= NN) d = 0;
    sS[tid] = (int)s; sD[tid] = (int)d;
  }
  f4 zero4 = {0.f,0.f,0.f,0.f};
  f4 acc[2][8];
  #pragma unroll
  for(int a=0;a<2;a++){
    #pragma unroll
    for(int b=0;b<8;b++) acc[a][b] = zero4;
  }
  for(int ks=0; ks<12; ks++){
    __syncthreads();
    #pragma unroll
    for(int i=0;i<2;i++){
      int idx = tid + i*256;
      int r = idx>>2, c8 = (idx&3)*8;
      int off = (ks&3)*32 + c8;
      int reg = ks>>2;
      bf8 v;
      if(reg==0)      v = ld8f(x + (size_t)sS[r]*128 + off);   // x[src] first here
      else if(reg==1) v = ld8f(x + (size_t)sD[r]*128 + off);
      else            v = *(const bf8*)(ea + (size_t)(ebase+r)*128 + off);
      *(bf8*)(At + r*40 + c8) = v;
    }
    __syncthreads();
    bf8 bfr[8];
    #pragma unroll
    for(int cf=0;cf<8;cf++)
      bfr[cf] = *(const bf8*)(Wf1 + ((size_t)((ks*8+cf)*64 + lane))*8);
    #pragma unroll
    for(int rf=0;rf<2;rf++){
      bf8 a = *(const bf8*)(At + (wv*32 + rf*16 + l16)*40 + quad*8);
      #pragma unroll
      for(int cf=0;cf<8;cf++)
        acc[rf][cf] = __builtin_amdgcn_mfma_f32_16x16x32_bf16(a, bfr[cf], acc[rf][cf], 0,0,0);
    }
  }
  // relu(+b1) -> Ot
  #pragma unroll
  for(int rf=0;rf<2;rf++){
    #pragma unroll
    for(int cf=0;cf<8;cf++){
      int col = cf*16 + l16;
      float bv = b1[col];
      #pragma unroll
      for(int r=0;r<4;r++){
        int row = wv*32 + rf*16 + quad*4 + r;
        float v = acc[rf][cf][r] + bv;
        Ot[row*136 + col] = f2bf(v > 0.f ? fin(v) : 0.f);
      }
    }
  }
  __syncthreads();
  f4 acc2[2][8];
  #pragma unroll
  for(int a=0;a<2;a++){
    #pragma unroll
    for(int b=0;b<8;b++) acc2[a][b] = zero4;
  }
  for(int ks=0; ks<4; ks++){
    bf8 bfr[8];
    #pragma unroll
    for(int cf=0;cf<8;cf++)
      bfr[cf] = *(const bf8*)(Wf2 + ((size_t)((ks*8+cf)*64 + lane))*8);
    #pragma unroll
    for(int rf=0;rf<2;rf++){
      bf8 a = *(const bf8*)(Ot + (wv*32 + rf*16 + l16)*136 + ks*32 + quad*8);
      #pragma unroll
      for(int cf=0;cf<8;cf++)
        acc2[rf][cf] = __builtin_amdgcn_mfma_f32_16x16x32_bf16(a, bfr[cf], acc2[rf][cf], 0,0,0);
    }
  }
  __syncthreads();
  #pragma unroll
  for(int rf=0;rf<2;rf++){
    #pragma unroll
    for(int cf=0;cf<8;cf++){
      int col = cf*16 + l16;
      float bv = b2[col];
      #pragma unroll
      for(int r=0;r<4;r++){
        int row = wv*32 + rf*16 + quad*4 + r;
        Ot[row*136 + col] = f2bf(0.5f*(acc2[rf][cf][r] + bv));
      }
    }
  }
  __syncthreads();
  #pragma unroll
  for(int i=0;i<8;i++){
    int idx = tid + i*256;
    int r = idx>>4, c8 = (idx&15)*8;
    size_t gidx = (size_t)(ebase+r)*128 + c8;
    bf8 e = *(const bf8*)(ea + gidx);
    bf8 o = *(const bf8*)(Ot + r*136 + c8);
    bf8 res;
    #pragma unroll
    for(int jj=0;jj<8;jj++) res[jj] = (short)f2bf(fin(bf2f((u16)e[jj]) + bf2f((u16)o[jj])));
    *(bf8*)(ea + gidx) = res;
  }
}

// ---------------- launcher ----------------
extern "C" void kernel_launch(void* const* d_in, const int* in_sizes, int n_in,
                              void* d_out, int out_size, void* d_ws, size_t ws_size,
                              hipStream_t stream)
{
  const float* x_in   = (const float*)d_in[0];
  const int*   ei     = (const int*)d_in[1];
  const float* eatt   = (const float*)d_in[2];
  const float* patt   = (const float*)d_in[4];
  const float* natt   = (const float*)d_in[6];
  const float* w_node = (const float*)d_in[8];
  const float* b_node = (const float*)d_in[9];
  const float* w_edge = (const float*)d_in[10];
  const float* b_edge = (const float*)d_in[11];
  const float* eenc_w = (const float*)d_in[12];
  const float* eenc_b = (const float*)d_in[13];
  const float* pre_w  = (const float*)d_in[14];
  const float* pre_b  = (const float*)d_in[15];
  const float* post_w = (const float*)d_in[16];
  const float* post_b = (const float*)d_in[17];
  const float* lin_w  = (const float*)d_in[18];
  const float* lin_b  = (const float*)d_in[19];
  const float* emlp_w1= (const float*)d_in[20];
  const float* emlp_b1= (const float*)d_in[21];
  const float* emlp_w2= (const float*)d_in[22];
  const float* emlp_b2= (const float*)d_in[23];
  const float* bn_g   = (const float*)d_in[24];
  const float* bn_b   = (const float*)d_in[25];

  float* xcur  = (float*)d_out;                   // x (f32) lives in d_out
  float* pos_o = xcur + (size_t)NN*HD;
  float* neg_o = pos_o + (size_t)NEP*HD;

  // ---- workspace layout (no aliasing; ~237 MB) ----
  char* p = (char*)d_ws;
  auto alloc = [&](size_t b)->void*{ void* r = (void*)p; p += (b + 255) & ~(size_t)255; return r; };
  u16*   ea     = (u16*)  alloc((size_t)NE*HD*2);      // 102.4 MB (internal bf16)
  u16*   hperm  = (u16*)  alloc((size_t)HCAP*HD*2);    //  53.8 MB
  u16*   agg    = (u16*)  alloc((size_t)NN*4*HD*2);    //  51.2 MB
  float* out2   = (float*)alloc((size_t)NN*HD*4);      //  25.6 MB
  int*   deg    = (int*)  alloc((size_t)NN*4);
  int*   cursor = (int*)  alloc((size_t)NN*4);
  int*   rowptr = (int*)  alloc((size_t)(NN+1)*4);
  int*   eids   = (int*)  alloc((size_t)NE*4);
  float* amp    = (float*)alloc((size_t)NN*4);
  float* att    = (float*)alloc((size_t)NN*4);
  float* adlbuf = (float*)alloc(256);
  float* biasH  = (float*)alloc((size_t)NL*HD*4);
  u16*   BpreP  = (u16*)  alloc((size_t)NL*384*HD*2);
  u16*   f_node = (u16*)  alloc((size_t)64*HD*2);
  u16*   f_edge = (u16*)  alloc((size_t)32*HD*2);
  u16*   f_pre  = (u16*)  alloc((size_t)NL*384*HD*2);
  u16*   f_e1   = (u16*)  alloc((size_t)NL*384*HD*2);
  u16*   f_e2   = (u16*)  alloc((size_t)NL*HD*HD*2);
  u16*   f_lin  = (u16*)  alloc((size_t)NL*HD*HD*2);
  u16*   f_post = (u16*)  alloc((size_t)NL*1664*HD*2);
  float* S      = (float*)alloc((size_t)2*HD*4);

  k_zero    <<<(NN+255)/256, 256, 0, stream>>>(deg, NN);
  k_zero    <<<(NN+255)/256, 256, 0, stream>>>(cursor, NN);
  k_deg     <<<(NE+255)/256, 256, 0, stream>>>(ei, deg);
  k_adl     <<<1, 1024, 0, stream>>>(deg, adlbuf);
  k_scan    <<<1, 1024, 0, stream>>>(deg, rowptr);
  k_nodeprep<<<(NN+255)/256, 256, 0, stream>>>(deg, adlbuf, amp, att);
  k_fill    <<<(NE+255)/256, 256, 0, stream>>>(ei, rowptr, cursor, eids);
  k_fold_row <<<NL*129, 128, 0, stream>>>(eenc_w, eenc_b, pre_w, pre_b, BpreP, biasH);
  k_fold_copy<<<(NL*256*HD+255)/256, 256, 0, stream>>>(pre_w, BpreP);

  FragJobs J;
  int u = 0, ji = 0;
  auto addjob = [&](const void* s, u16* d, int K, int f32){
    J.src[ji] = s; J.dst[ji] = d; J.isf32[ji] = f32; u += K*16; J.end[ji] = u; ji++; };
  addjob(w_node, f_node, 64, 1);
  addjob(w_edge, f_edge, 32, 1);
  for(int l=0;l<NL;l++) addjob(BpreP   + l*384*HD, f_pre  + l*384*HD, 384, 0);
  for(int l=0;l<NL;l++) addjob(emlp_w1 + l*384*HD, f_e1   + l*384*HD, 384, 1);
  for(int l=0;l<NL;l++) addjob(emlp_w2 + l*HD*HD,  f_e2   + l*HD*HD,  128, 1);
  for(int l=0;l<NL;l++) addjob(lin_w   + l*HD*HD,  f_lin  + l*HD*HD,  128, 1);
  for(int l=0;l<NL;l++) addjob(post_w  + l*1664*HD,f_post + l*1664*HD,1664, 1);
  k_fragB<<<(u+255)/256, 256, 0, stream>>>(J);

  k_gemm_rm<<<(NN+127)/128, 256, 0, stream>>>(x_in, f_node, b_node, xcur, NN, FD, 0);
  k_gemm_rm<<<NE/128,        256, 0, stream>>>(eatt, f_edge, b_edge, ea,    NE, EDD, 1);
  k_gemm_rm<<<(NEP+127)/128, 256, 0, stream>>>(patt, f_edge, b_edge, pos_o, NEP, EDD, 0);
  k_gemm_rm<<<(NEP+127)/128, 256, 0, stream>>>(natt, f_edge, b_edge, neg_o, NEP, EDD, 0);

  const int NHALF = NN/2;   // 25000
  const int HGRID = (HCAP + 127)/128;   // 1641 blocks: covers any chunk (<= HCAP rows)
  for(int l=0; l<NL; l++){
    for(int c=0; c<2; c++){
      int n0 = c*NHALF, n1 = (c==1) ? NN : (c+1)*NHALF;
      k_gemm_h_perm<<<HGRID, 256, 0, stream>>>(xcur, ea, ei, eids, rowptr, n0, n1,
                     f_pre + l*384*HD, biasH + l*HD, hperm);
      k_agg_csr    <<<n1-n0, 128, 0, stream>>>(hperm, rowptr, n0, agg);
    }
    k_gemm_post<<<(NN+127)/128, 256, 0, stream>>>(xcur, agg, amp, att,
                  f_post + l*1664*HD, post_b + l*HD, f_lin + l*HD*HD, lin_b + l*HD, out2);
    k_zero     <<<1, 256, 0, stream>>>((int*)S, 2*HD);
    k_bnstats  <<<512, 128, 0, stream>>>(out2, S);
    k_xupd     <<<(NN*HD)/256, 256, 0, stream>>>(out2, S, bn_g + l*HD, bn_b + l*HD, xcur);
    k_gemm_emlp<<<NE/128, 256, 0, stream>>>(xcur, ea, ei, f_e1 + l*384*HD, emlp_b1 + l*HD,
                  f_e2 + l*HD*HD, emlp_b2 + l*HD);
  }
}